// Round 12
// baseline (2990.643 us; speedup 1.0000x reference)
//
#include <hip/hip_runtime.h>

typedef unsigned short u16;
typedef unsigned int   u32;
typedef __attribute__((ext_vector_type(8))) short bh8;
typedef __attribute__((ext_vector_type(4))) float f4;

constexpr int BATCH = 8, HIDN = 1024, NHEAD = 8, HD = 256, NLAY = 18, DMLP = 4096;
constexpr int AHOR = 50, ADIMN = 32, PFXN = 1037, SEQN = 1087, MR = 400, MP = 512;
constexpr int NGRP = 9; // 9 key-groups of 128 (1152 >= 1087)
constexpr float EPSV = 1e-6f, NEGV = -2.3819763e38f, QSCALE = 0.0625f;
constexpr size_t ADASL = (size_t)37 * 3 * BATCH * HIDN; // 909312
// padded LDS strides (u16 units): gcd(stride/2, 32) == 1 -> conflict-free fragment reads
constexpr int SW64 = 90, SW32 = 138, SKT = 266, SPT = 74, SVT = 90;

static __device__ __forceinline__ u16 f2bf(float x){
  union{float f; u32 u;} v; v.f = x;
  u32 r = (v.u + 0x7FFFu + ((v.u >> 16) & 1u)) >> 16;
  return (u16)r;
}
static __device__ __forceinline__ float bf2f(u16 u){
  union{u32 u; float f;} v; v.u = ((u32)u) << 16; return v.f;
}
static __device__ __forceinline__ u32 pack2(float a, float b){
  return (u32)f2bf(a) | ((u32)f2bf(b) << 16);
}
static __device__ __forceinline__ f4 MFMA(bh8 a, bh8 b, f4 c){
  return __builtin_amdgcn_mfma_f32_16x16x32_bf16(a, b, c, 0, 0, 0);
}
static __device__ __forceinline__ float siluf_(float x){ return x / (1.f + __expf(-x)); }
static __device__ __forceinline__ float geluf_(float x){
  float y = 0.7978845608028654f * (x + 0.044715f * x * x * x);
  float e = __expf(2.f * y);
  return 0.5f * x * (2.f - 2.f / (e + 1.f));
}

// ---------------- prep: temb, offs, rope tables ----------------
__global__ void k_prep(const int* __restrict__ mask, const float* __restrict__ ts,
                       float* __restrict__ temb, int* __restrict__ offs,
                       float* __restrict__ ropec, float* __restrict__ ropes)
{
  int t = threadIdx.x;
  {
    int b = t >> 5, l = t & 31;
    const int* mp = mask + b * PFXN;
    int s = 0;
    for (int k = l; k < PFXN; k += 32) s += (mp[k] != 0);
    #pragma unroll
    for (int off = 16; off >= 1; off >>= 1) s += __shfl_xor(s, off);
    if (l == 0) offs[b] = s;
  }
  for (int i = t; i < BATCH * 512; i += 256){
    int b = i >> 9, j = i & 511;
    float frac = (float)j * (1.0f / 511.0f);
    float period = 0.004f * __expf(frac * 6.907755278982137f);
    float arg = (6.283185307179586f / period) * ts[b];
    float s, c; sincosf(arg, &s, &c);
    temb[b * HIDN + j] = s;
    temb[b * HIDN + 512 + j] = c;
  }
  __syncthreads();
  for (int i = t; i < BATCH * AHOR * 128; i += 256){
    int d = i & 127, bt = i >> 7, b = bt / AHOR, tt = bt % AHOR;
    float inv = __expf(-((float)d * (1.f / 128.f)) * 9.210340371976184f);
    float arg = (float)(offs[b] + tt) * inv;
    float s, c; sincosf(arg, &s, &c);
    ropec[i] = c; ropes[i] = s;
  }
}

// ---------------- tiny M=8 GEMM (1024x1024) + silu ----------------
__global__ void k_tproj(const float* __restrict__ X, const float* __restrict__ W,
                        const float* __restrict__ bias, float* __restrict__ out)
{
  __shared__ float xs[BATCH * HIDN];
  __shared__ float red[BATCH][8][32];
  int t = threadIdx.x;
  for (int i = t; i < BATCH * HIDN; i += 256) xs[i] = X[i];
  __syncthreads();
  int c = t & 31, kp = t >> 5;
  int c0 = blockIdx.x * 32;
  float acc[BATCH];
  #pragma unroll
  for (int b = 0; b < BATCH; ++b) acc[b] = 0.f;
  for (int k = kp * 128; k < kp * 128 + 128; ++k){
    float w = W[(size_t)k * HIDN + c0 + c];
    #pragma unroll
    for (int b = 0; b < BATCH; ++b) acc[b] += xs[b * HIDN + k] * w;
  }
  #pragma unroll
  for (int b = 0; b < BATCH; ++b) red[b][kp][c] = acc[b];
  __syncthreads();
  int b2 = t >> 5, c2 = t & 31;
  float s = bias[c0 + c2];
  #pragma unroll
  for (int kp2 = 0; kp2 < 8; ++kp2) s += red[b2][kp2][c2];
  out[b2 * HIDN + c0 + c2] = siluf_(s);
}

// ---------------- ada partial: K-split x8, batched f4 loads ----------------
__global__ void k_ada_part(const float* __restrict__ cond, const float* __restrict__ A1,
                           const float* __restrict__ A2, const float* __restrict__ Af,
                           float* __restrict__ adap)
{
  __shared__ float cs[BATCH * 128];
  int t = threadIdx.x;
  int y = blockIdx.y, ks = blockIdx.z;
  int k0 = ks * 128;
  for (int i = t; i < BATCH * 128; i += 256){
    int b = i >> 7, kk = i & 127;
    cs[i] = cond[b * HIDN + k0 + kk];
  }
  __syncthreads();
  const float* A = (y < NLAY) ? (A1 + (size_t)y * HIDN * 3072)
                  : (y < 2 * NLAY) ? (A2 + (size_t)(y - NLAY) * HIDN * 3072) : Af;
  int n = (blockIdx.x * 256 + t) * 4;
  f4 acc[BATCH];
  #pragma unroll
  for (int b = 0; b < BATCH; ++b) acc[b] = (f4){0.f,0.f,0.f,0.f};
  const float* ap = A + (size_t)k0 * 3072 + n;
  for (int kk = 0; kk < 128; kk += 8){
    f4 av[8];
    #pragma unroll
    for (int j = 0; j < 8; ++j) av[j] = *(const f4*)(ap + (size_t)(kk + j) * 3072);
    #pragma unroll
    for (int j = 0; j < 8; ++j){
      #pragma unroll
      for (int b = 0; b < BATCH; ++b) acc[b] += av[j] * cs[b * 128 + kk + j];
    }
  }
  int comp = n >> 10, nn = n & 1023;
  float* o = adap + (size_t)ks * ADASL + ((size_t)y * 3 + comp) * BATCH * HIDN + nn;
  #pragma unroll
  for (int b = 0; b < BATCH; ++b) *(f4*)(o + b * HIDN) = acc[b];
}

__global__ void k_ada_red(const float* __restrict__ adap, float* __restrict__ ada)
{
  size_t i = ((size_t)blockIdx.x * 256 + threadIdx.x) * 8;
  f4 a0 = {0,0,0,0}, a1 = {0,0,0,0};
  #pragma unroll
  for (int ks = 0; ks < 8; ++ks){
    const float* p = adap + (size_t)ks * ADASL + i;
    a0 += *(const f4*)p;
    a1 += *(const f4*)(p + 4);
  }
  *(f4*)(ada + i) = a0;
  *(f4*)(ada + i + 4) = a1;
}

// ---------------- h0 = x_t @ W_act_in + b ----------------
__global__ void k_hin(const float* __restrict__ xt, const float* __restrict__ W,
                      const float* __restrict__ bias, float* __restrict__ h)
{
  int r = blockIdx.x;
  int t = threadIdx.x; int c0 = t * 4;
  __shared__ float xs[ADIMN];
  if (t < ADIMN) xs[t] = xt[r * ADIMN + t];
  __syncthreads();
  float a0 = bias[c0], a1 = bias[c0+1], a2 = bias[c0+2], a3 = bias[c0+3];
  for (int k = 0; k < ADIMN; ++k){
    float x = xs[k];
    const float* wp = W + k * HIDN + c0;
    a0 += x * wp[0]; a1 += x * wp[1]; a2 += x * wp[2]; a3 += x * wp[3];
  }
  float* hp = h + (size_t)r * HIDN + c0;
  hp[0] = a0; hp[1] = a1; hp[2] = a2; hp[3] = a3;
}

// ---------------- residual + RMS + AdaNorm -> fragA bf16 (2 rows/block, 256 blocks) ----------------
__global__ void k_resnorm(int mode, int np,
    const float* __restrict__ base, const u16* __restrict__ parts,
    const float* __restrict__ gate, const float* __restrict__ sc,
    const float* __restrict__ sh, float* __restrict__ outres,
    u16* __restrict__ fragA)
{
  __shared__ float redl[4];
  int t = threadIdx.x;
  int c = t * 4;
  for (int i = 0; i < 2; ++i){
    int r = blockIdx.x * 2 + i;
    bool live = (r < MR);
    float4 v = {0.f,0.f,0.f,0.f};
    int b = live ? (r / AHOR) : 0;
    if (live){
      v = *(const float4*)(base + (size_t)r * HIDN + c);
      if (mode){
        float s0 = 0, s1 = 0, s2 = 0, s3 = 0;
        #pragma unroll 4
        for (int p = 0; p < np; ++p){
          ushort4 u4 = *(const ushort4*)(parts + ((size_t)p * MP + r) * HIDN + c);
          s0 += bf2f(u4.x); s1 += bf2f(u4.y); s2 += bf2f(u4.z); s3 += bf2f(u4.w);
        }
        float4 gp = *(const float4*)(gate + b * HIDN + c);
        v.x += gp.x * s0; v.y += gp.y * s1; v.z += gp.z * s2; v.w += gp.w * s3;
        *(float4*)(outres + (size_t)r * HIDN + c) = v;
      }
    }
    float ss = v.x*v.x + v.y*v.y + v.z*v.z + v.w*v.w;
    #pragma unroll
    for (int off = 1; off < 64; off <<= 1) ss += __shfl_xor(ss, off);
    if ((t & 63) == 0) redl[t >> 6] = ss;
    __syncthreads();
    float tot = redl[0] + redl[1] + redl[2] + redl[3];
    __syncthreads();
    u16* dst = fragA + ((size_t)(c >> 3)) * MP * 8 + (size_t)r * 8 + (c & 7);
    ushort4 ov;
    if (live){
      float rstd = rsqrtf(tot * (1.0f / HIDN) + EPSV);
      const float4 scp = *(const float4*)(sc + b * HIDN + c);
      const float4 shp = *(const float4*)(sh + b * HIDN + c);
      ov.x = f2bf(v.x * rstd * (1.f + scp.x) + shp.x);
      ov.y = f2bf(v.y * rstd * (1.f + scp.y) + shp.y);
      ov.z = f2bf(v.z * rstd * (1.f + scp.z) + shp.z);
      ov.w = f2bf(v.w * rstd * (1.f + scp.w) + shp.w);
    } else {
      ov.x = ov.y = ov.z = ov.w = 0;
    }
    *(ushort4*)dst = ov;
  }
}

// ---------------- GEMM core 64-col: dbuf LDS (pad 90), depth-3 W prefetch, dbuf A ----------------
template<int NOUTER>
static __device__ __forceinline__ void gemm_core64(
    const u16* __restrict__ fa,
    const float* __restrict__ Wa, int cb0,
    const float* __restrict__ Wb, int cb1,
    int wN, int kc0, u16* lds, f4 acc[4][4])
{
  const int tid = threadIdx.x;
  const int lane = tid & 63, wave = tid >> 6;
  const int l15 = lane & 15, g = lane >> 4;
  const int wrow = wave * 64;
  const int c4 = (tid & 15) * 4;
  const int r0 = (tid >> 4) * 2;
  const float* wcol = (c4 < 32) ? (Wa + cb0 + c4) : (Wb + cb1 + (c4 - 32));
  const size_t krow0 = (size_t)kc0 * 8 + r0;
  f4 preA[3], preB[3];
  bh8 ab[2][2][4];
  preA[0] = *(const f4*)(wcol + krow0 * wN);
  preB[0] = *(const f4*)(wcol + (krow0 + 1) * wN);
  #pragma unroll
  for (int kk = 0; kk < 2; ++kk){
    const u16* ap = fa + ((size_t)(kc0 + kk * 4 + g) * MP + wrow + l15) * 8;
    #pragma unroll
    for (int mf = 0; mf < 4; ++mf) ab[0][kk][mf] = *(const bh8*)(ap + mf * 128);
  }
  if (NOUTER > 1){
    preA[1] = *(const f4*)(wcol + (krow0 + 64) * wN);
    preB[1] = *(const f4*)(wcol + (krow0 + 65) * wN);
  }
  if (NOUTER > 2){
    preA[2] = *(const f4*)(wcol + (krow0 + 128) * wN);
    preB[2] = *(const f4*)(wcol + (krow0 + 129) * wN);
  }
  #pragma unroll
  for (int i = 0; i < 4; ++i)
    *(u32*)(lds + (c4 + i) * SW64 + r0) = pack2(preA[0][i], preB[0][i]);
  __syncthreads();
  #pragma unroll
  for (int ko = 0; ko < NOUTER; ++ko){
    u16* ldsr = lds + (ko & 1) * (64 * SW64);
    if (ko + 1 < NOUTER){
      #pragma unroll
      for (int kk = 0; kk < 2; ++kk){
        const u16* ap = fa + ((size_t)(kc0 + (ko + 1) * 8 + kk * 4 + g) * MP + wrow + l15) * 8;
        #pragma unroll
        for (int mf = 0; mf < 4; ++mf) ab[(ko + 1) & 1][kk][mf] = *(const bh8*)(ap + mf * 128);
      }
    }
    if (ko + 3 < NOUTER){
      preA[ko % 3] = *(const f4*)(wcol + (krow0 + (size_t)(ko + 3) * 64) * wN);
      preB[ko % 3] = *(const f4*)(wcol + (krow0 + (size_t)(ko + 3) * 64 + 1) * wN);
    }
    #pragma unroll
    for (int kk = 0; kk < 2; ++kk){
      bh8 bb[4];
      #pragma unroll
      for (int nf = 0; nf < 4; ++nf) bb[nf] = *(const bh8*)(ldsr + (nf * 16 + l15) * SW64 + kk * 32 + g * 8);
      #pragma unroll
      for (int mf = 0; mf < 4; ++mf)
        #pragma unroll
        for (int nf = 0; nf < 4; ++nf)
          acc[mf][nf] = MFMA(ab[ko & 1][kk][mf], bb[nf], acc[mf][nf]);
    }
    if (ko + 1 < NOUTER){
      u16* ldsw = lds + ((ko + 1) & 1) * (64 * SW64);
      const int sl = (ko + 1) % 3;
      #pragma unroll
      for (int i = 0; i < 4; ++i)
        *(u32*)(ldsw + (c4 + i) * SW64 + r0) = pack2(preA[sl][i], preB[sl][i]);
      __syncthreads();
    }
  }
}

// ---------------- GEMM core 32-col wide-K: 128 k/iter, dbuf LDS (pad 138), depth-3 ----------------
template<int NOUTER>
static __device__ __forceinline__ void gemm_core32w(
    const u16* __restrict__ fa,
    const float* __restrict__ Wa, int cb0,
    const float* __restrict__ Wb, int cb1,
    int wN, u16* lds, f4 acc[4][2])
{
  const int tid = threadIdx.x;
  const int lane = tid & 63, wave = tid >> 6;
  const int l15 = lane & 15, g = lane >> 4;
  const int wrow = wave * 64;
  const int c4 = (tid & 7) * 4;
  const int r0 = (tid >> 3) * 2;
  const float* wcol = (c4 < 16) ? (Wa + cb0 + c4) : (Wb + cb1 + (c4 - 16));
  f4 preA[3], preB[3];
  preA[0] = *(const f4*)(wcol + (size_t)r0 * wN);
  preB[0] = *(const f4*)(wcol + (size_t)(r0 + 1) * wN);
  if (NOUTER > 1){
    preA[1] = *(const f4*)(wcol + (size_t)(128 + r0) * wN);
    preB[1] = *(const f4*)(wcol + (size_t)(129 + r0) * wN);
  }
  if (NOUTER > 2){
    preA[2] = *(const f4*)(wcol + (size_t)(256 + r0) * wN);
    preB[2] = *(const f4*)(wcol + (size_t)(257 + r0) * wN);
  }
  #pragma unroll
  for (int i = 0; i < 4; ++i)
    *(u32*)(lds + (c4 + i) * SW32 + r0) = pack2(preA[0][i], preB[0][i]);
  __syncthreads();
  #pragma unroll
  for (int ko = 0; ko < NOUTER; ++ko){
    u16* ldsr = lds + (ko & 1) * (32 * SW32);
    bh8 a01[2][4], a23[2][4];
    #pragma unroll
    for (int kk = 0; kk < 2; ++kk){
      const u16* ap = fa + ((size_t)(ko * 16 + kk * 4 + g) * MP + wrow + l15) * 8;
      #pragma unroll
      for (int mf = 0; mf < 4; ++mf) a01[kk][mf] = *(const bh8*)(ap + mf * 128);
    }
    if (ko + 3 < NOUTER){
      preA[ko % 3] = *(const f4*)(wcol + (size_t)((ko + 3) * 128 + r0) * wN);
      preB[ko % 3] = *(const f4*)(wcol + (size_t)((ko + 3) * 128 + r0 + 1) * wN);
    }
    #pragma unroll
    for (int kk = 2; kk < 4; ++kk){
      const u16* ap = fa + ((size_t)(ko * 16 + kk * 4 + g) * MP + wrow + l15) * 8;
      #pragma unroll
      for (int mf = 0; mf < 4; ++mf) a23[kk - 2][mf] = *(const bh8*)(ap + mf * 128);
    }
    #pragma unroll
    for (int kk = 0; kk < 2; ++kk){
      bh8 bb[2];
      #pragma unroll
      for (int nf = 0; nf < 2; ++nf) bb[nf] = *(const bh8*)(ldsr + (nf * 16 + l15) * SW32 + kk * 32 + g * 8);
      #pragma unroll
      for (int mf = 0; mf < 4; ++mf){
        acc[mf][0] = MFMA(a01[kk][mf], bb[0], acc[mf][0]);
        acc[mf][1] = MFMA(a01[kk][mf], bb[1], acc[mf][1]);
      }
    }
    #pragma unroll
    for (int kk = 2; kk < 4; ++kk){
      bh8 bb[2];
      #pragma unroll
      for (int nf = 0; nf < 2; ++nf) bb[nf] = *(const bh8*)(ldsr + (nf * 16 + l15) * SW32 + kk * 32 + g * 8);
      #pragma unroll
      for (int mf = 0; mf < 4; ++mf){
        acc[mf][0] = MFMA(a23[kk - 2][mf], bb[0], acc[mf][0]);
        acc[mf][1] = MFMA(a23[kk - 2][mf], bb[1], acc[mf][1]);
      }
    }
    if (ko + 1 < NOUTER){
      u16* ldsw = lds + ((ko + 1) & 1) * (32 * SW32);
      const int sl = (ko + 1) % 3;
      #pragma unroll
      for (int i = 0; i < 4; ++i)
        *(u32*)(ldsw + (c4 + i) * SW32 + r0) = pack2(preA[sl][i], preB[sl][i]);
      __syncthreads();
    }
  }
}

// ---------------- fused QKV GEMM (K=1024, 16+16 col tiles) + RoPE epilogue, 80 blocks ----------------
__global__ __launch_bounds__(512) void k_qkvrope(
    const u16* __restrict__ n1, const float* __restrict__ Wq,
    const float* __restrict__ Wk, const float* __restrict__ Wv,
    const float* __restrict__ ropec, const float* __restrict__ ropes,
    u16* __restrict__ qf, u16* __restrict__ ks, u16* __restrict__ vs)
{
  __shared__ u16 lds[2 * 32 * SW32];
  int bx = blockIdx.x;
  const float *Wa, *Wb; int cb0, cb1, wN, type, head = 0, fb = 0, d0 = 0;
  if (bx < 64){ type = 0; head = bx >> 3; fb = (bx & 7) * 16; Wa = Wq; Wb = Wq; wN = NHEAD * HD; cb0 = head * HD + fb; cb1 = cb0 + 128; }
  else if (bx < 72){ type = 1; fb = (bx - 64) * 16; Wa = Wk; Wb = Wk; wN = HD; cb0 = fb; cb1 = fb + 128; }
  else { type = 2; d0 = (bx - 72) * 32; Wa = Wv; Wb = Wv; wN = HD; cb0 = d0; cb1 = d0 + 16; }
  f4 acc[4][2];
  #pragma unroll
  for (int i = 0; i < 4; ++i)
    #pragma unroll
    for (int j = 0; j < 2; ++j) acc[i][j] = (f4){0.f, 0.f, 0.f, 0.f};
  gemm_core32w<8>(n1, Wa, cb0, Wb, cb1, wN, lds, acc);
  int tid = threadIdx.x, lane = tid & 63, wave = tid >> 6, l15 = lane & 15, g = lane >> 4;
  int wrow = wave * 64;
  #pragma unroll
  for (int mf = 0; mf < 4; ++mf)
    #pragma unroll
    for (int r = 0; r < 4; ++r){
      int row = wrow + mf * 16 + 4 * g + r;
      if (row >= MR) continue;
      int b = row / AHOR, tt = row - b * AHOR;
      float lo = acc[mf][0][r], hi = acc[mf][1][r];
      if (type == 2){
        size_t vb = ((size_t)(b * AHOR + tt)) * HD;
        vs[vb + d0 + l15] = f2bf(lo);
        vs[vb + d0 + 16 + l15] = f2bf(hi);
      } else {
        int dA = fb + l15;
        float cz = ropec[(size_t)(b * AHOR + tt) * 128 + dA];
        float sz = ropes[(size_t)(b * AHOR + tt) * 128 + dA];
        float oA = lo * cz - hi * sz;
        float oB = hi * cz + lo * sz;
        if (type == 0){
          oA *= QSCALE; oB *= QSCALE;
          int rowp = head * AHOR + tt;
          int dB = dA + 128;
          qf[((size_t)(b * 32 + (dA >> 3))) * MP * 8 + (size_t)rowp * 8 + (dA & 7)] = f2bf(oA);
          qf[((size_t)(b * 32 + (dB >> 3))) * MP * 8 + (size_t)rowp * 8 + (dB & 7)] = f2bf(oB);
        } else {
          size_t kb = ((size_t)(b * AHOR + tt)) * HD;
          ks[kb + dA] = f2bf(oA);
          ks[kb + dA + 128] = f2bf(oB);
        }
      }
    }
}

// ---------------- attention: per (128-key group, batch, M-half), online 2-tile flash ----------------
__global__ __launch_bounds__(512) void k_attn(
    const u16* __restrict__ qf, const u16* __restrict__ kss, const u16* __restrict__ vss,
    const float* __restrict__ pk, const float* __restrict__ pv,
    const int* __restrict__ mask, int layer,
    u16* __restrict__ opart, float* __restrict__ mrow, float* __restrict__ lrow)
{
  __shared__ u16 kv[256 * SVT];   // union: K [64][266] / V^T [256][90] skewed
  __shared__ u16 plds[256 * SPT];
  int s = blockIdx.x, b = blockIdx.y, z = blockIdx.z;
  int tid = threadIdx.x, lane = tid & 63, wave = tid >> 6, l15 = lane & 15, g = lane >> 4;
  int zb = z * 256;
  int wbase = wave * 32;
  // online state + O accumulators
  f4 oc[4][2][4]; // [dc][mf][nf]
  #pragma unroll
  for (int dc = 0; dc < 4; ++dc)
    #pragma unroll
    for (int mf = 0; mf < 2; ++mf)
      #pragma unroll
      for (int nf = 0; nf < 4; ++nf) oc[dc][mf][nf] = (f4){0.f,0.f,0.f,0.f};
  float mrun[2][4], lrun[2][4];
  #pragma unroll
  for (int mf = 0; mf < 2; ++mf)
    #pragma unroll
    for (int r = 0; r < 4; ++r){ mrun[mf][r] = -3.0e38f; lrun[mf][r] = 0.f; }

  #pragma unroll
  for (int kt = 0; kt < 2; ++kt){
    int kbase = s * 128 + kt * 64;
    { // stage K tile (64 keys x 256 d)
      int key = tid >> 3, dblk = (tid & 7) * 32;
      int kg = kbase + key;
      u32* dst = (u32*)(kv + key * SKT + dblk);
      if (kg < PFXN){
        const float4* src = (const float4*)(pk + (((size_t)b * NLAY + layer) * PFXN + kg) * HD + dblk);
        #pragma unroll
        for (int j = 0; j < 8; ++j){ float4 v = src[j]; dst[2*j] = pack2(v.x, v.y); dst[2*j+1] = pack2(v.z, v.w); }
      } else if (kg < SEQN){
        const u32* src = (const u32*)(kss + ((size_t)b * AHOR + (kg - PFXN)) * HD + dblk);
        #pragma unroll
        for (int j = 0; j < 16; ++j) dst[j] = src[j];
      } else {
        #pragma unroll
        for (int j = 0; j < 16; ++j) dst[j] = 0;
      }
    }
    // prefetch V tile into regs (T14: hides under QK^T + softmax)
    float vreg[32];
    int vkey = tid >> 3, vdb = (tid & 7) * 32;
    {
      int kgv = kbase + vkey;
      if (kgv < PFXN){
        const float4* src = (const float4*)(pv + (((size_t)b * NLAY + layer) * PFXN + kgv) * HD + vdb);
        #pragma unroll
        for (int j = 0; j < 8; ++j){ float4 v = src[j]; vreg[4*j] = v.x; vreg[4*j+1] = v.y; vreg[4*j+2] = v.z; vreg[4*j+3] = v.w; }
      } else if (kgv < SEQN){
        const u32* src = (const u32*)(vss + ((size_t)b * AHOR + (kgv - PFXN)) * HD + vdb);
        #pragma unroll
        for (int j = 0; j < 16; ++j){ u32 u = src[j]; vreg[2*j] = bf2f((u16)(u & 0xFFFF)); vreg[2*j+1] = bf2f((u16)(u >> 16)); }
      } else {
        #pragma unroll
        for (int j = 0; j < 32; ++j) vreg[j] = 0.f;
      }
    }
    bool valid[4];
    #pragma unroll
    for (int nf = 0; nf < 4; ++nf){
      int kgc = kbase + nf * 16 + l15;
      valid[nf] = (kgc < PFXN) ? (mask[b * PFXN + kgc] != 0) : (kgc < SEQN);
    }
    __syncthreads();
    // S = (Q*scale) K^T for this row-half
    f4 acc[2][4];
    #pragma unroll
    for (int i = 0; i < 2; ++i)
      #pragma unroll
      for (int j = 0; j < 4; ++j) acc[i][j] = (f4){0.f,0.f,0.f,0.f};
    const u16* qb = qf + (size_t)b * 32 * MP * 8;
    #pragma unroll
    for (int ko = 0; ko < 4; ++ko)
      #pragma unroll
      for (int kk = 0; kk < 2; ++kk){
        int kc = ko * 8 + kk * 4 + g;
        bh8 a[2], bb[4];
        const u16* ap = qb + ((size_t)kc * MP + zb + wbase + l15) * 8;
        #pragma unroll
        for (int mf = 0; mf < 2; ++mf) a[mf] = *(const bh8*)(ap + mf * 128);
        #pragma unroll
        for (int nf = 0; nf < 4; ++nf) bb[nf] = *(const bh8*)(kv + (nf * 16 + l15) * SKT + ko * 64 + kk * 32 + g * 8);
        #pragma unroll
        for (int mf = 0; mf < 2; ++mf)
          #pragma unroll
          for (int nf = 0; nf < 4; ++nf) acc[mf][nf] = MFMA(a[mf], bb[nf], acc[mf][nf]);
      }
    #pragma unroll
    for (int nf = 0; nf < 4; ++nf) if (!valid[nf]){
      #pragma unroll
      for (int mf = 0; mf < 2; ++mf){
        acc[mf][nf][0] = NEGV; acc[mf][nf][1] = NEGV; acc[mf][nf][2] = NEGV; acc[mf][nf][3] = NEGV;
      }
    }
    // online softmax update + P write + O rescale
    #pragma unroll
    for (int mf = 0; mf < 2; ++mf)
      #pragma unroll
      for (int r = 0; r < 4; ++r){
        float mt = fmaxf(fmaxf(acc[mf][0][r], acc[mf][1][r]), fmaxf(acc[mf][2][r], acc[mf][3][r]));
        #pragma unroll
        for (int off = 1; off < 16; off <<= 1) mt = fmaxf(mt, __shfl_xor(mt, off));
        float mnew = fmaxf(mrun[mf][r], mt);
        float alpha = __expf(mrun[mf][r] - mnew);
        int lr = wbase + mf * 16 + 4 * g + r;
        float sum = 0.f;
        #pragma unroll
        for (int nf = 0; nf < 4; ++nf){
          float p = __expf(acc[mf][nf][r] - mnew);
          sum += p;
          plds[lr * SPT + nf * 16 + l15] = f2bf(p);
        }
        #pragma unroll
        for (int off = 1; off < 16; off <<= 1) sum += __shfl_xor(sum, off);
        lrun[mf][r] = alpha * lrun[mf][r] + sum;
        mrun[mf][r] = mnew;
        #pragma unroll
        for (int dc = 0; dc < 4; ++dc)
          #pragma unroll
          for (int nf = 0; nf < 4; ++nf) oc[dc][mf][nf][r] *= alpha;
      }
    __syncthreads();
    { // write V^T from regs (skewed, stride SVT)
      #pragma unroll
      for (int j = 0; j < 32; ++j){
        int dloc = vdb + j;
        kv[dloc * SVT + ((dloc >> 5) & 3) * 8 + vkey] = f2bf(vreg[j]);
      }
    }
    __syncthreads();
    // O += P V
    #pragma unroll
    for (int dc = 0; dc < 4; ++dc){
      #pragma unroll
      for (int kk = 0; kk < 2; ++kk){
        bh8 a[2], bb[4];
        #pragma unroll
        for (int mf = 0; mf < 2; ++mf) a[mf] = *(const bh8*)(plds + (wbase + mf * 16 + l15) * SPT + kk * 32 + g * 8);
        #pragma unroll
        for (int nf = 0; nf < 4; ++nf){
          int dcol = dc * 64 + nf * 16 + l15;
          bb[nf] = *(const bh8*)(kv + dcol * SVT + ((dcol >> 5) & 3) * 8 + kk * 32 + g * 8);
        }
        #pragma unroll
        for (int mf = 0; mf < 2; ++mf)
          #pragma unroll
          for (int nf = 0; nf < 4; ++nf) oc[dc][mf][nf] = MFMA(a[mf], bb[nf], oc[dc][mf][nf]);
      }
    }
    __syncthreads(); // LDS reuse next sub-tile
  }
  // epilogue: running max/sum + unnormalized O
  #pragma unroll
  for (int mf = 0; mf < 2; ++mf)
    #pragma unroll
    for (int r = 0; r < 4; ++r){
      int lr = wbase + mf * 16 + 4 * g + r;
      if (l15 == 0){
        mrow[((size_t)b * NGRP + s) * MP + zb + lr] = mrun[mf][r];
        lrow[((size_t)b * NGRP + s) * MP + zb + lr] = lrun[mf][r];
      }
    }
  #pragma unroll
  for (int dc = 0; dc < 4; ++dc)
    #pragma unroll
    for (int mf = 0; mf < 2; ++mf)
      #pragma unroll
      for (int r = 0; r < 4; ++r){
        int row = zb + wbase + mf * 16 + 4 * g + r;
        if (row < MR){
          #pragma unroll
          for (int nf = 0; nf < 4; ++nf){
            int d = dc * 64 + nf * 16 + l15;
            opart[(((size_t)b * NGRP + s) * MR + row) * HD + d] = f2bf(oc[dc][mf][nf][r]);
          }
        }
      }
}

// ---------------- combine groups -> attn_out fragA (vectorized: 4 d/thread) ----------------
__global__ void k_comb(const u16* __restrict__ opart, const float* __restrict__ mrow,
                       const float* __restrict__ lrow, u16* __restrict__ ao)
{
  int b = blockIdx.y;
  int t = threadIdx.x; // 256
  int d4 = (t & 63) * 4;
  int row = blockIdx.x * 4 + (t >> 6);
  float M = -3.0e38f;
  for (int s2 = 0; s2 < NGRP; ++s2) M = fmaxf(M, mrow[((size_t)b * NGRP + s2) * MP + row]);
  float L = 0.f;
  float o0 = 0.f, o1 = 0.f, o2 = 0.f, o3 = 0.f;
  for (int s2 = 0; s2 < NGRP; ++s2){
    float w = __expf(mrow[((size_t)b * NGRP + s2) * MP + row] - M);
    L += w * lrow[((size_t)b * NGRP + s2) * MP + row];
    ushort4 u4 = *(const ushort4*)(opart + (((size_t)b * NGRP + s2) * MR + row) * HD + d4);
    o0 += w * bf2f(u4.x); o1 += w * bf2f(u4.y); o2 += w * bf2f(u4.z); o3 += w * bf2f(u4.w);
  }
  float rL = 1.0f / L;
  int h = row / AHOR, tt = row - h * AHOR;
  int col = h * HD + d4;
  int rg = b * AHOR + tt;
  ushort4 ov;
  ov.x = f2bf(o0 * rL); ov.y = f2bf(o1 * rL); ov.z = f2bf(o2 * rL); ov.w = f2bf(o3 * rL);
  *(ushort4*)(ao + ((size_t)(col >> 3)) * MP * 8 + (size_t)rg * 8 + (col & 7)) = ov;
}

// ---------------- split-K GEMM -> bf16 partials (O-proj / MLP-down) ----------------
template<int NOUTER>
__global__ __launch_bounds__(512) void k_gemm_part(
    const u16* __restrict__ fa, const float* __restrict__ W, int wN,
    int kcPerSlice, u16* __restrict__ outp)
{
  __shared__ u16 lds[2 * 64 * SW64];
  int n0 = blockIdx.x * 64;
  int ksl = blockIdx.y;
  f4 acc[4][4];
  #pragma unroll
  for (int i = 0; i < 4; ++i)
    #pragma unroll
    for (int j = 0; j < 4; ++j) acc[i][j] = (f4){0.f,0.f,0.f,0.f};
  gemm_core64<NOUTER>(fa, W, n0, W, n0 + 32, wN, ksl * kcPerSlice, lds, acc);
  int tid = threadIdx.x, lane = tid & 63, wave = tid >> 6, l15 = lane & 15, g = lane >> 4;
  int wrow = wave * 64;
  #pragma unroll
  for (int mf = 0; mf < 4; ++mf)
    #pragma unroll
    for (int r = 0; r < 4; ++r){
      int row = wrow + mf * 16 + 4 * g + r;
      #pragma unroll
      for (int nf = 0; nf < 4; ++nf)
        outp[((size_t)ksl * MP + row) * 1024 + n0 + nf * 16 + l15] = f2bf(acc[mf][nf][r]);
    }
}

// ---------------- MLP up: gelu(n2@Wg) * (n2@Wu) -> fragA ----------------
__global__ __launch_bounds__(512) void k_mlpup(
    const u16* __restrict__ n2, const float* __restrict__ Wg, const float* __restrict__ Wu,
    u16* __restrict__ mlpf)
{
  __shared__ u16 lds[2 * 32 * SW32];
  int n0 = blockIdx.x * 16;
  f4 acc[4][2];
  #pragma unroll
  for (int i = 0; i < 4; ++i)
    #pragma unroll
    for (int j = 0; j < 2; ++j) acc[i][j] = (f4){0.f,0.f,0.f,0.f};
  gemm_core32w<8>(n2, Wg, n0, Wu, n0, DMLP, lds, acc);
  int tid = threadIdx.x, lane = tid & 63, wave = tid >> 6, l15 = lane & 15, g = lane >> 4;
  int wrow = wave * 64;
  #pragma unroll
  for (int mf = 0; mf < 4; ++mf)
    #pragma unroll
    for (int r = 0; r < 4; ++r){
      int row = wrow + mf * 16 + 4 * g + r;
      int col = n0 + l15;
      float gg = acc[mf][0][r], uu = acc[mf][1][r];
      float act = geluf_(gg) * uu;
      mlpf[((size_t)(col >> 3)) * MP * 8 + (size_t)row * 8 + (col & 7)] = f2bf(act);
    }
}

// ---------------- final: out = nf @ W_act_out + b (vectorized bh8 A-reads) ----------------
__global__ void k_out(const u16* __restrict__ nfr, const float* __restrict__ W,
                      const float* __restrict__ bias, float* __restrict__ out)
{
  int t = threadIdx.x;
  int row = blockIdx.x * 8 + (t >> 5);
  int c = t & 31;
  float acc = bias[c];
  for (int kc = 0; kc < 128; ++kc){
    bh8 v = *(const bh8*)(nfr + ((size_t)kc * MP + row) * 8);
    #pragma unroll
    for (int j = 0; j < 8; ++j)
      acc += bf2f((u16)v[j]) * W[(kc * 8 + j) * ADIMN + c];
  }
  out[row * ADIMN + c] = acc;
}

extern "C" void kernel_launch(void* const* d_in, const int* in_sizes, int n_in,
                              void* d_out, int out_size, void* d_ws, size_t ws_size,
                              hipStream_t stream)
{
  const float* pk  = (const float*)d_in[0];
  const float* pv  = (const float*)d_in[1];
  const int*   msk = (const int*)d_in[2];
  const float* xt  = (const float*)d_in[3];
  const float* ts  = (const float*)d_in[4];
  const float* Wq  = (const float*)d_in[5];
  const float* Wk  = (const float*)d_in[6];
  const float* Wv  = (const float*)d_in[7];
  const float* Wo  = (const float*)d_in[8];
  const float* Wg  = (const float*)d_in[9];
  const float* Wu  = (const float*)d_in[10];
  const float* Wd  = (const float*)d_in[11];
  const float* A1  = (const float*)d_in[12];
  const float* A2  = (const float*)d_in[13];
  const float* Af  = (const float*)d_in[14];
  const float* Wai = (const float*)d_in[15];
  const float* bai = (const float*)d_in[16];
  const float* Wao = (const float*)d_in[17];
  const float* bao = (const float*)d_in[18];
  const float* Wti = (const float*)d_in[19];
  const float* bti = (const float*)d_in[20];
  const float* Wto = (const float*)d_in[21];
  const float* bto = (const float*)d_in[22];

  char* w = (char*)d_ws;
  size_t off = 0;
  auto alloc = [&](size_t bytes) -> char* {
    char* p = w + off; off += (bytes + 255) & ~(size_t)255; return p;
  };
  float* temb  = (float*)alloc((size_t)BATCH * HIDN * 4);
  float* ttmp  = (float*)alloc((size_t)BATCH * HIDN * 4);
  float* cond  = (float*)alloc((size_t)BATCH * HIDN * 4);
  int*   offs  = (int*)alloc(BATCH * 4);
  float* ropec = (float*)alloc((size_t)BATCH * AHOR * 128 * 4);
  float* ropes = (float*)alloc((size_t)BATCH * AHOR * 128 * 4);
  float* ada   = (float*)alloc(ADASL * 4);
  float* adap  = (float*)alloc(8 * ADASL * 4);
  float* h     = (float*)alloc((size_t)MR * HIDN * 4);
  float* h1    = (float*)alloc((size_t)MR * HIDN * 4);
  u16*   n1    = (u16*)alloc((size_t)128 * MP * 8 * 2);
  u16*   n2    = (u16*)alloc((size_t)128 * MP * 8 * 2);
  u16*   qf    = (u16*)alloc((size_t)BATCH * 32 * MP * 8 * 2);
  u16*   kss   = (u16*)alloc((size_t)BATCH * AHOR * HD * 2);
  u16*   vss   = (u16*)alloc((size_t)BATCH * AHOR * HD * 2);
  u16*   opart = (u16*)alloc((size_t)BATCH * NGRP * MR * HD * 2);
  float* mrow  = (float*)alloc((size_t)BATCH * NGRP * MP * 4);
  float* lrow  = (float*)alloc((size_t)BATCH * NGRP * MP * 4);
  u16*   ao    = (u16*)alloc((size_t)256 * MP * 8 * 2);
  u16*   opp   = (u16*)alloc((size_t)8 * MP * 1024 * 2);
  u16*   mlpf  = (u16*)alloc((size_t)512 * MP * 8 * 2);
  u16*   mdp   = (u16*)alloc((size_t)8 * MP * 1024 * 2);
  if (off > ws_size) return;

  k_prep<<<1, 256, 0, stream>>>(msk, ts, temb, offs, ropec, ropes);
  k_tproj<<<32, 256, 0, stream>>>(temb, Wti, bti, ttmp);
  k_tproj<<<32, 256, 0, stream>>>(ttmp, Wto, bto, cond);
  k_ada_part<<<dim3(3, 37, 8), 256, 0, stream>>>(cond, A1, A2, Af, adap);
  k_ada_red<<<444, 256, 0, stream>>>(adap, ada);
  k_hin<<<MR, 256, 0, stream>>>(xt, Wai, bai, h);

  auto AP = [&](int y, int comp){ return ada + ((size_t)y * 3 + comp) * BATCH * HIDN; };

  k_resnorm<<<256, 256, 0, stream>>>(0, 0, h, nullptr, nullptr, AP(0,0), AP(0,1), nullptr, n1);

  for (int l = 0; l < NLAY; ++l){
    k_qkvrope<<<80, 512, 0, stream>>>(n1, Wq + (size_t)l * HIDN * NHEAD * HD,
                                      Wk + (size_t)l * HIDN * HD, Wv + (size_t)l * HIDN * HD,
                                      ropec, ropes, qf, kss, vss);
    k_attn<<<dim3(NGRP, BATCH, 2), 512, 0, stream>>>(qf, kss, vss, pk, pv, msk, l, opart, mrow, lrow);
    k_comb<<<dim3(100, BATCH), 256, 0, stream>>>(opart, mrow, lrow, ao);
    k_gemm_part<4><<<dim3(16, 8), 512, 0, stream>>>(ao, Wo + (size_t)l * 2048 * 1024, 1024, 32, opp);
    k_resnorm<<<256, 256, 0, stream>>>(1, 8, h, opp, AP(l,2), AP(NLAY+l,0), AP(NLAY+l,1), h1, n2);
    k_mlpup<<<256, 512, 0, stream>>>(n2, Wg + (size_t)l * HIDN * DMLP, Wu + (size_t)l * HIDN * DMLP, mlpf);
    k_gemm_part<8><<<dim3(16, 8), 512, 0, stream>>>(mlpf, Wd + (size_t)l * DMLP * 1024, 1024, 64, mdp);
    const float* nsc = (l < NLAY - 1) ? AP(l + 1, 0) : AP(36, 0);
    const float* nsh = (l < NLAY - 1) ? AP(l + 1, 1) : AP(36, 1);
    k_resnorm<<<256, 256, 0, stream>>>(2, 8, h1, mdp, AP(NLAY+l,2), nsc, nsh, h, n1);
  }
  k_out<<<50, 256, 0, stream>>>(n1, Wao, bao, (float*)d_out);
}

// Round 13
// 2831.804 us; speedup vs baseline: 1.0561x; 1.0561x over previous
//
#include <hip/hip_runtime.h>

typedef unsigned short u16;
typedef unsigned int   u32;
typedef __attribute__((ext_vector_type(8))) short bh8;
typedef __attribute__((ext_vector_type(4))) float f4;

constexpr int BATCH = 8, HIDN = 1024, NHEAD = 8, HD = 256, NLAY = 18, DMLP = 4096;
constexpr int AHOR = 50, ADIMN = 32, PFXN = 1037, SEQN = 1087, NSTR = 17, MR = 400, MP = 512;
constexpr float EPSV = 1e-6f, NEGV = -2.3819763e38f, QSCALE = 0.0625f;
constexpr size_t ADASL = (size_t)37 * 3 * BATCH * HIDN; // 909312
// padded LDS strides (u16 units): gcd(stride/2, 32) == 1 -> conflict-free fragment reads
constexpr int SW64 = 90, SW32 = 138, SKT = 266, SPT = 74, SVT = 90;

static __device__ __forceinline__ u16 f2bf(float x){
  union{float f; u32 u;} v; v.f = x;
  u32 r = (v.u + 0x7FFFu + ((v.u >> 16) & 1u)) >> 16;
  return (u16)r;
}
static __device__ __forceinline__ float bf2f(u16 u){
  union{u32 u; float f;} v; v.u = ((u32)u) << 16; return v.f;
}
static __device__ __forceinline__ u32 pack2(float a, float b){
  return (u32)f2bf(a) | ((u32)f2bf(b) << 16);
}
static __device__ __forceinline__ f4 MFMA(bh8 a, bh8 b, f4 c){
  return __builtin_amdgcn_mfma_f32_16x16x32_bf16(a, b, c, 0, 0, 0);
}
static __device__ __forceinline__ float siluf_(float x){ return x / (1.f + __expf(-x)); }
static __device__ __forceinline__ float geluf_(float x){
  float y = 0.7978845608028654f * (x + 0.044715f * x * x * x);
  float e = __expf(2.f * y);
  return 0.5f * x * (2.f - 2.f / (e + 1.f));
}

// ---------------- prep: temb, offs, rope tables ----------------
__global__ void k_prep(const int* __restrict__ mask, const float* __restrict__ ts,
                       float* __restrict__ temb, int* __restrict__ offs,
                       float* __restrict__ ropec, float* __restrict__ ropes)
{
  int t = threadIdx.x;
  {
    int b = t >> 5, l = t & 31;
    const int* mp = mask + b * PFXN;
    int s = 0;
    for (int k = l; k < PFXN; k += 32) s += (mp[k] != 0);
    #pragma unroll
    for (int off = 16; off >= 1; off >>= 1) s += __shfl_xor(s, off);
    if (l == 0) offs[b] = s;
  }
  for (int i = t; i < BATCH * 512; i += 256){
    int b = i >> 9, j = i & 511;
    float frac = (float)j * (1.0f / 511.0f);
    float period = 0.004f * __expf(frac * 6.907755278982137f);
    float arg = (6.283185307179586f / period) * ts[b];
    float s, c; sincosf(arg, &s, &c);
    temb[b * HIDN + j] = s;
    temb[b * HIDN + 512 + j] = c;
  }
  __syncthreads();
  for (int i = t; i < BATCH * AHOR * 128; i += 256){
    int d = i & 127, bt = i >> 7, b = bt / AHOR, tt = bt % AHOR;
    float inv = __expf(-((float)d * (1.f / 128.f)) * 9.210340371976184f);
    float arg = (float)(offs[b] + tt) * inv;
    float s, c; sincosf(arg, &s, &c);
    ropec[i] = c; ropes[i] = s;
  }
}

// ---------------- tiny M=8 GEMM (1024x1024) + silu ----------------
__global__ void k_tproj(const float* __restrict__ X, const float* __restrict__ W,
                        const float* __restrict__ bias, float* __restrict__ out)
{
  __shared__ float xs[BATCH * HIDN];
  __shared__ float red[BATCH][8][32];
  int t = threadIdx.x;
  for (int i = t; i < BATCH * HIDN; i += 256) xs[i] = X[i];
  __syncthreads();
  int c = t & 31, kp = t >> 5;
  int c0 = blockIdx.x * 32;
  float acc[BATCH];
  #pragma unroll
  for (int b = 0; b < BATCH; ++b) acc[b] = 0.f;
  for (int k = kp * 128; k < kp * 128 + 128; ++k){
    float w = W[(size_t)k * HIDN + c0 + c];
    #pragma unroll
    for (int b = 0; b < BATCH; ++b) acc[b] += xs[b * HIDN + k] * w;
  }
  #pragma unroll
  for (int b = 0; b < BATCH; ++b) red[b][kp][c] = acc[b];
  __syncthreads();
  int b2 = t >> 5, c2 = t & 31;
  float s = bias[c0 + c2];
  #pragma unroll
  for (int kp2 = 0; kp2 < 8; ++kp2) s += red[b2][kp2][c2];
  out[b2 * HIDN + c0 + c2] = siluf_(s);
}

// ---------------- ada partial: K-split x8, batched f4 loads ----------------
__global__ void k_ada_part(const float* __restrict__ cond, const float* __restrict__ A1,
                           const float* __restrict__ A2, const float* __restrict__ Af,
                           float* __restrict__ adap)
{
  __shared__ float cs[BATCH * 128];
  int t = threadIdx.x;
  int y = blockIdx.y, ks = blockIdx.z;
  int k0 = ks * 128;
  for (int i = t; i < BATCH * 128; i += 256){
    int b = i >> 7, kk = i & 127;
    cs[i] = cond[b * HIDN + k0 + kk];
  }
  __syncthreads();
  const float* A = (y < NLAY) ? (A1 + (size_t)y * HIDN * 3072)
                  : (y < 2 * NLAY) ? (A2 + (size_t)(y - NLAY) * HIDN * 3072) : Af;
  int n = (blockIdx.x * 256 + t) * 4;
  f4 acc[BATCH];
  #pragma unroll
  for (int b = 0; b < BATCH; ++b) acc[b] = (f4){0.f,0.f,0.f,0.f};
  const float* ap = A + (size_t)k0 * 3072 + n;
  for (int kk = 0; kk < 128; kk += 8){
    f4 av[8];
    #pragma unroll
    for (int j = 0; j < 8; ++j) av[j] = *(const f4*)(ap + (size_t)(kk + j) * 3072);
    #pragma unroll
    for (int j = 0; j < 8; ++j){
      #pragma unroll
      for (int b = 0; b < BATCH; ++b) acc[b] += av[j] * cs[b * 128 + kk + j];
    }
  }
  int comp = n >> 10, nn = n & 1023;
  float* o = adap + (size_t)ks * ADASL + ((size_t)y * 3 + comp) * BATCH * HIDN + nn;
  #pragma unroll
  for (int b = 0; b < BATCH; ++b) *(f4*)(o + b * HIDN) = acc[b];
}

__global__ void k_ada_red(const float* __restrict__ adap, float* __restrict__ ada)
{
  size_t i = ((size_t)blockIdx.x * 256 + threadIdx.x) * 8;
  f4 a0 = {0,0,0,0}, a1 = {0,0,0,0};
  #pragma unroll
  for (int ks = 0; ks < 8; ++ks){
    const float* p = adap + (size_t)ks * ADASL + i;
    a0 += *(const f4*)p;
    a1 += *(const f4*)(p + 4);
  }
  *(f4*)(ada + i) = a0;
  *(f4*)(ada + i + 4) = a1;
}

// ---------------- h0 = x_t @ W_act_in + b ----------------
__global__ void k_hin(const float* __restrict__ xt, const float* __restrict__ W,
                      const float* __restrict__ bias, float* __restrict__ h)
{
  int r = blockIdx.x;
  int t = threadIdx.x; int c0 = t * 4;
  __shared__ float xs[ADIMN];
  if (t < ADIMN) xs[t] = xt[r * ADIMN + t];
  __syncthreads();
  float a0 = bias[c0], a1 = bias[c0+1], a2 = bias[c0+2], a3 = bias[c0+3];
  for (int k = 0; k < ADIMN; ++k){
    float x = xs[k];
    const float* wp = W + k * HIDN + c0;
    a0 += x * wp[0]; a1 += x * wp[1]; a2 += x * wp[2]; a3 += x * wp[3];
  }
  float* hp = h + (size_t)r * HIDN + c0;
  hp[0] = a0; hp[1] = a1; hp[2] = a2; hp[3] = a3;
}

// ---------------- residual + RMS + AdaNorm -> fragA bf16 (2 rows/block, 256 blocks) ----------------
__global__ void k_resnorm(int mode, int np,
    const float* __restrict__ base, const u16* __restrict__ parts,
    const float* __restrict__ gate, const float* __restrict__ sc,
    const float* __restrict__ sh, float* __restrict__ outres,
    u16* __restrict__ fragA)
{
  __shared__ float redl[4];
  int t = threadIdx.x;
  int c = t * 4;
  for (int i = 0; i < 2; ++i){
    int r = blockIdx.x * 2 + i;
    bool live = (r < MR);
    float4 v = {0.f,0.f,0.f,0.f};
    int b = live ? (r / AHOR) : 0;
    if (live){
      v = *(const float4*)(base + (size_t)r * HIDN + c);
      if (mode){
        float s0 = 0, s1 = 0, s2 = 0, s3 = 0;
        #pragma unroll 4
        for (int p = 0; p < np; ++p){
          ushort4 u4 = *(const ushort4*)(parts + ((size_t)p * MP + r) * HIDN + c);
          s0 += bf2f(u4.x); s1 += bf2f(u4.y); s2 += bf2f(u4.z); s3 += bf2f(u4.w);
        }
        float4 gp = *(const float4*)(gate + b * HIDN + c);
        v.x += gp.x * s0; v.y += gp.y * s1; v.z += gp.z * s2; v.w += gp.w * s3;
        *(float4*)(outres + (size_t)r * HIDN + c) = v;
      }
    }
    float ss = v.x*v.x + v.y*v.y + v.z*v.z + v.w*v.w;
    #pragma unroll
    for (int off = 1; off < 64; off <<= 1) ss += __shfl_xor(ss, off);
    if ((t & 63) == 0) redl[t >> 6] = ss;
    __syncthreads();
    float tot = redl[0] + redl[1] + redl[2] + redl[3];
    __syncthreads();
    u16* dst = fragA + ((size_t)(c >> 3)) * MP * 8 + (size_t)r * 8 + (c & 7);
    ushort4 ov;
    if (live){
      float rstd = rsqrtf(tot * (1.0f / HIDN) + EPSV);
      const float4 scp = *(const float4*)(sc + b * HIDN + c);
      const float4 shp = *(const float4*)(sh + b * HIDN + c);
      ov.x = f2bf(v.x * rstd * (1.f + scp.x) + shp.x);
      ov.y = f2bf(v.y * rstd * (1.f + scp.y) + shp.y);
      ov.z = f2bf(v.z * rstd * (1.f + scp.z) + shp.z);
      ov.w = f2bf(v.w * rstd * (1.f + scp.w) + shp.w);
    } else {
      ov.x = ov.y = ov.z = ov.w = 0;
    }
    *(ushort4*)dst = ov;
  }
}

// ---------------- GEMM core 32-col wide-K: 128 k/iter, dbuf LDS (pad 138), depth-3 ----------------
template<int NOUTER>
static __device__ __forceinline__ void gemm_core32w(
    const u16* __restrict__ fa,
    const float* __restrict__ Wa, int cb0,
    const float* __restrict__ Wb, int cb1,
    int wN, u16* lds, f4 acc[4][2])
{
  const int tid = threadIdx.x;
  const int lane = tid & 63, wave = tid >> 6;
  const int l15 = lane & 15, g = lane >> 4;
  const int wrow = wave * 64;
  const int c4 = (tid & 7) * 4;
  const int r0 = (tid >> 3) * 2;
  const float* wcol = (c4 < 16) ? (Wa + cb0 + c4) : (Wb + cb1 + (c4 - 16));
  f4 preA[3], preB[3];
  preA[0] = *(const f4*)(wcol + (size_t)r0 * wN);
  preB[0] = *(const f4*)(wcol + (size_t)(r0 + 1) * wN);
  if (NOUTER > 1){
    preA[1] = *(const f4*)(wcol + (size_t)(128 + r0) * wN);
    preB[1] = *(const f4*)(wcol + (size_t)(129 + r0) * wN);
  }
  if (NOUTER > 2){
    preA[2] = *(const f4*)(wcol + (size_t)(256 + r0) * wN);
    preB[2] = *(const f4*)(wcol + (size_t)(257 + r0) * wN);
  }
  #pragma unroll
  for (int i = 0; i < 4; ++i)
    *(u32*)(lds + (c4 + i) * SW32 + r0) = pack2(preA[0][i], preB[0][i]);
  __syncthreads();
  #pragma unroll
  for (int ko = 0; ko < NOUTER; ++ko){
    u16* ldsr = lds + (ko & 1) * (32 * SW32);
    bh8 a01[2][4], a23[2][4];
    #pragma unroll
    for (int kk = 0; kk < 2; ++kk){
      const u16* ap = fa + ((size_t)(ko * 16 + kk * 4 + g) * MP + wrow + l15) * 8;
      #pragma unroll
      for (int mf = 0; mf < 4; ++mf) a01[kk][mf] = *(const bh8*)(ap + mf * 128);
    }
    if (ko + 3 < NOUTER){
      preA[ko % 3] = *(const f4*)(wcol + (size_t)((ko + 3) * 128 + r0) * wN);
      preB[ko % 3] = *(const f4*)(wcol + (size_t)((ko + 3) * 128 + r0 + 1) * wN);
    }
    #pragma unroll
    for (int kk = 2; kk < 4; ++kk){
      const u16* ap = fa + ((size_t)(ko * 16 + kk * 4 + g) * MP + wrow + l15) * 8;
      #pragma unroll
      for (int mf = 0; mf < 4; ++mf) a23[kk - 2][mf] = *(const bh8*)(ap + mf * 128);
    }
    #pragma unroll
    for (int kk = 0; kk < 2; ++kk){
      bh8 bb[2];
      #pragma unroll
      for (int nf = 0; nf < 2; ++nf) bb[nf] = *(const bh8*)(ldsr + (nf * 16 + l15) * SW32 + kk * 32 + g * 8);
      #pragma unroll
      for (int mf = 0; mf < 4; ++mf){
        acc[mf][0] = MFMA(a01[kk][mf], bb[0], acc[mf][0]);
        acc[mf][1] = MFMA(a01[kk][mf], bb[1], acc[mf][1]);
      }
    }
    #pragma unroll
    for (int kk = 2; kk < 4; ++kk){
      bh8 bb[2];
      #pragma unroll
      for (int nf = 0; nf < 2; ++nf) bb[nf] = *(const bh8*)(ldsr + (nf * 16 + l15) * SW32 + kk * 32 + g * 8);
      #pragma unroll
      for (int mf = 0; mf < 4; ++mf){
        acc[mf][0] = MFMA(a23[kk - 2][mf], bb[0], acc[mf][0]);
        acc[mf][1] = MFMA(a23[kk - 2][mf], bb[1], acc[mf][1]);
      }
    }
    if (ko + 1 < NOUTER){
      u16* ldsw = lds + ((ko + 1) & 1) * (32 * SW32);
      const int sl = (ko + 1) % 3;
      #pragma unroll
      for (int i = 0; i < 4; ++i)
        *(u32*)(ldsw + (c4 + i) * SW32 + r0) = pack2(preA[sl][i], preB[sl][i]);
      __syncthreads();
    }
  }
}

// ---------------- fused QKV GEMM (K=1024, 16+16 col tiles) + RoPE epilogue, 80 blocks ----------------
__global__ __launch_bounds__(512) void k_qkvrope(
    const u16* __restrict__ n1, const float* __restrict__ Wq,
    const float* __restrict__ Wk, const float* __restrict__ Wv,
    const float* __restrict__ ropec, const float* __restrict__ ropes,
    u16* __restrict__ qf, u16* __restrict__ ks, u16* __restrict__ vs)
{
  __shared__ u16 lds[2 * 32 * SW32];
  int bx = blockIdx.x;
  const float *Wa, *Wb; int cb0, cb1, wN, type, head = 0, fb = 0, d0 = 0;
  if (bx < 64){ type = 0; head = bx >> 3; fb = (bx & 7) * 16; Wa = Wq; Wb = Wq; wN = NHEAD * HD; cb0 = head * HD + fb; cb1 = cb0 + 128; }
  else if (bx < 72){ type = 1; fb = (bx - 64) * 16; Wa = Wk; Wb = Wk; wN = HD; cb0 = fb; cb1 = fb + 128; }
  else { type = 2; d0 = (bx - 72) * 32; Wa = Wv; Wb = Wv; wN = HD; cb0 = d0; cb1 = d0 + 16; }
  f4 acc[4][2];
  #pragma unroll
  for (int i = 0; i < 4; ++i)
    #pragma unroll
    for (int j = 0; j < 2; ++j) acc[i][j] = (f4){0.f, 0.f, 0.f, 0.f};
  gemm_core32w<8>(n1, Wa, cb0, Wb, cb1, wN, lds, acc);
  int tid = threadIdx.x, lane = tid & 63, wave = tid >> 6, l15 = lane & 15, g = lane >> 4;
  int wrow = wave * 64;
  #pragma unroll
  for (int mf = 0; mf < 4; ++mf)
    #pragma unroll
    for (int r = 0; r < 4; ++r){
      int row = wrow + mf * 16 + 4 * g + r;
      if (row >= MR) continue;
      int b = row / AHOR, tt = row - b * AHOR;
      float lo = acc[mf][0][r], hi = acc[mf][1][r];
      if (type == 2){
        size_t vb = ((size_t)(b * AHOR + tt)) * HD;
        vs[vb + d0 + l15] = f2bf(lo);
        vs[vb + d0 + 16 + l15] = f2bf(hi);
      } else {
        int dA = fb + l15;
        float cz = ropec[(size_t)(b * AHOR + tt) * 128 + dA];
        float sz = ropes[(size_t)(b * AHOR + tt) * 128 + dA];
        float oA = lo * cz - hi * sz;
        float oB = hi * cz + lo * sz;
        if (type == 0){
          oA *= QSCALE; oB *= QSCALE;
          int rowp = head * AHOR + tt;
          int dB = dA + 128;
          qf[((size_t)(b * 32 + (dA >> 3))) * MP * 8 + (size_t)rowp * 8 + (dA & 7)] = f2bf(oA);
          qf[((size_t)(b * 32 + (dB >> 3))) * MP * 8 + (size_t)rowp * 8 + (dB & 7)] = f2bf(oB);
        } else {
          size_t kb = ((size_t)(b * AHOR + tt)) * HD;
          ks[kb + dA] = f2bf(oA);
          ks[kb + dA + 128] = f2bf(oB);
        }
      }
    }
}

// ---------------- attention: per (strip, batch, M-half) flash partial (r11-proven) ----------------
__global__ __launch_bounds__(512) void k_attn(
    const u16* __restrict__ qf, const u16* __restrict__ kss, const u16* __restrict__ vss,
    const float* __restrict__ pk, const float* __restrict__ pv,
    const int* __restrict__ mask, int layer,
    u16* __restrict__ opart, float* __restrict__ mrow, float* __restrict__ lrow)
{
  __shared__ u16 kv[256 * SVT];   // union: K [64][266] / V^T [256][90] skewed
  __shared__ u16 plds[256 * SPT];
  int s = blockIdx.x, b = blockIdx.y, z = blockIdx.z;
  int tid = threadIdx.x, lane = tid & 63, wave = tid >> 6, l15 = lane & 15, g = lane >> 4;
  int zb = z * 256;
  int wbase = wave * 32;
  { // stage K tile (full 256 d, 64 keys)
    int key = tid >> 3, dblk = (tid & 7) * 32;
    int kg = s * 64 + key;
    u32* dst = (u32*)(kv + key * SKT + dblk);
    if (kg < PFXN){
      const float4* src = (const float4*)(pk + (((size_t)b * NLAY + layer) * PFXN + kg) * HD + dblk);
      #pragma unroll
      for (int j = 0; j < 8; ++j){ float4 v = src[j]; dst[2*j] = pack2(v.x, v.y); dst[2*j+1] = pack2(v.z, v.w); }
    } else if (kg < SEQN){
      const u32* src = (const u32*)(kss + ((size_t)b * AHOR + (kg - PFXN)) * HD + dblk);
      #pragma unroll
      for (int j = 0; j < 16; ++j) dst[j] = src[j];
    } else {
      #pragma unroll
      for (int j = 0; j < 16; ++j) dst[j] = 0;
    }
  }
  // prefetch full-d V tile into registers (512 threads x 32 elems)
  float vreg[32];
  int vkey = tid >> 3, vdb = (tid & 7) * 32;
  {
    int kgv = s * 64 + vkey;
    if (kgv < PFXN){
      const float4* src = (const float4*)(pv + (((size_t)b * NLAY + layer) * PFXN + kgv) * HD + vdb);
      #pragma unroll
      for (int j = 0; j < 8; ++j){ float4 v = src[j]; vreg[4*j] = v.x; vreg[4*j+1] = v.y; vreg[4*j+2] = v.z; vreg[4*j+3] = v.w; }
    } else if (kgv < SEQN){
      const u32* src = (const u32*)(vss + ((size_t)b * AHOR + (kgv - PFXN)) * HD + vdb);
      #pragma unroll
      for (int j = 0; j < 16; ++j){ u32 u = src[j]; vreg[2*j] = bf2f((u16)(u & 0xFFFF)); vreg[2*j+1] = bf2f((u16)(u >> 16)); }
    } else {
      #pragma unroll
      for (int j = 0; j < 32; ++j) vreg[j] = 0.f;
    }
  }
  bool valid[4];
  #pragma unroll
  for (int nf = 0; nf < 4; ++nf){
    int kgc = s * 64 + nf * 16 + l15;
    valid[nf] = (kgc < PFXN) ? (mask[b * PFXN + kgc] != 0) : (kgc < SEQN);
  }
  __syncthreads();
  // S = (Q*scale) K^T for this row-half: acc[2][4]
  f4 acc[2][4];
  #pragma unroll
  for (int i = 0; i < 2; ++i)
    #pragma unroll
    for (int j = 0; j < 4; ++j) acc[i][j] = (f4){0.f,0.f,0.f,0.f};
  const u16* qb = qf + (size_t)b * 32 * MP * 8;
  #pragma unroll
  for (int ko = 0; ko < 4; ++ko)
    #pragma unroll
    for (int kk = 0; kk < 2; ++kk){
      int kc = ko * 8 + kk * 4 + g;
      bh8 a[2], bb[4];
      const u16* ap = qb + ((size_t)kc * MP + zb + wbase + l15) * 8;
      #pragma unroll
      for (int mf = 0; mf < 2; ++mf) a[mf] = *(const bh8*)(ap + mf * 128);
      #pragma unroll
      for (int nf = 0; nf < 4; ++nf) bb[nf] = *(const bh8*)(kv + (nf * 16 + l15) * SKT + ko * 64 + kk * 32 + g * 8);
      #pragma unroll
      for (int mf = 0; mf < 2; ++mf)
        #pragma unroll
        for (int nf = 0; nf < 4; ++nf) acc[mf][nf] = MFMA(a[mf], bb[nf], acc[mf][nf]);
    }
  #pragma unroll
  for (int nf = 0; nf < 4; ++nf) if (!valid[nf]){
    #pragma unroll
    for (int mf = 0; mf < 2; ++mf){
      acc[mf][nf][0] = NEGV; acc[mf][nf][1] = NEGV; acc[mf][nf][2] = NEGV; acc[mf][nf][3] = NEGV;
    }
  }
  // per-strip softmax (rows disjoint across z)
  #pragma unroll
  for (int mf = 0; mf < 2; ++mf)
    #pragma unroll
    for (int r = 0; r < 4; ++r){
      float m0 = fmaxf(fmaxf(acc[mf][0][r], acc[mf][1][r]), fmaxf(acc[mf][2][r], acc[mf][3][r]));
      #pragma unroll
      for (int off = 1; off < 16; off <<= 1) m0 = fmaxf(m0, __shfl_xor(m0, off));
      int lr = wbase + mf * 16 + 4 * g + r;
      float sum = 0.f;
      #pragma unroll
      for (int nf = 0; nf < 4; ++nf){
        float p = __expf(acc[mf][nf][r] - m0);
        sum += p;
        plds[lr * SPT + nf * 16 + l15] = f2bf(p);
      }
      #pragma unroll
      for (int off = 1; off < 16; off <<= 1) sum += __shfl_xor(sum, off);
      if (l15 == 0){
        mrow[((size_t)b * NSTR + s) * MP + zb + lr] = m0;
        lrow[((size_t)b * NSTR + s) * MP + zb + lr] = sum;
      }
    }
  __syncthreads();
  { // write V^T from regs (skewed, stride 90)
    #pragma unroll
    for (int j = 0; j < 32; ++j){
      int dloc = vdb + j;
      kv[dloc * SVT + ((dloc >> 5) & 3) * 8 + vkey] = f2bf(vreg[j]);
    }
  }
  __syncthreads();
  // O_part = P V (full 256 d for this row-half)
  #pragma unroll
  for (int dc = 0; dc < 4; ++dc){
    f4 oc[2][4];
    #pragma unroll
    for (int i = 0; i < 2; ++i)
      #pragma unroll
      for (int j = 0; j < 4; ++j) oc[i][j] = (f4){0.f,0.f,0.f,0.f};
    #pragma unroll
    for (int kk = 0; kk < 2; ++kk){
      bh8 a[2], bb[4];
      #pragma unroll
      for (int mf = 0; mf < 2; ++mf) a[mf] = *(const bh8*)(plds + (wbase + mf * 16 + l15) * SPT + kk * 32 + g * 8);
      #pragma unroll
      for (int nf = 0; nf < 4; ++nf){
        int dcol = dc * 64 + nf * 16 + l15;
        bb[nf] = *(const bh8*)(kv + dcol * SVT + ((dcol >> 5) & 3) * 8 + kk * 32 + g * 8);
      }
      #pragma unroll
      for (int mf = 0; mf < 2; ++mf)
        #pragma unroll
        for (int nf = 0; nf < 4; ++nf) oc[mf][nf] = MFMA(a[mf], bb[nf], oc[mf][nf]);
    }
    #pragma unroll
    for (int mf = 0; mf < 2; ++mf)
      #pragma unroll
      for (int r = 0; r < 4; ++r){
        int row = zb + wbase + mf * 16 + 4 * g + r;
        if (row < MR){
          #pragma unroll
          for (int nf = 0; nf < 4; ++nf){
            int d = dc * 64 + nf * 16 + l15;
            opart[(((size_t)b * NSTR + s) * MR + row) * HD + d] = f2bf(oc[mf][nf][r]);
          }
        }
      }
  }
}

// ---------------- combine strips -> attn_out fragA (vectorized: 4 d/thread) ----------------
__global__ void k_comb(const u16* __restrict__ opart, const float* __restrict__ mrow,
                       const float* __restrict__ lrow, u16* __restrict__ ao)
{
  int b = blockIdx.y;
  int t = threadIdx.x; // 256
  int d4 = (t & 63) * 4;
  int row = blockIdx.x * 4 + (t >> 6);
  float M = -3.0e38f;
  for (int s2 = 0; s2 < NSTR; ++s2) M = fmaxf(M, mrow[((size_t)b * NSTR + s2) * MP + row]);
  float L = 0.f;
  float o0 = 0.f, o1 = 0.f, o2 = 0.f, o3 = 0.f;
  for (int s2 = 0; s2 < NSTR; ++s2){
    float w = __expf(mrow[((size_t)b * NSTR + s2) * MP + row] - M);
    L += w * lrow[((size_t)b * NSTR + s2) * MP + row];
    ushort4 u4 = *(const ushort4*)(opart + (((size_t)b * NSTR + s2) * MR + row) * HD + d4);
    o0 += w * bf2f(u4.x); o1 += w * bf2f(u4.y); o2 += w * bf2f(u4.z); o3 += w * bf2f(u4.w);
  }
  float rL = 1.0f / L;
  int h = row / AHOR, tt = row - h * AHOR;
  int col = h * HD + d4;
  int rg = b * AHOR + tt;
  ushort4 ov;
  ov.x = f2bf(o0 * rL); ov.y = f2bf(o1 * rL); ov.z = f2bf(o2 * rL); ov.w = f2bf(o3 * rL);
  *(ushort4*)(ao + ((size_t)(col >> 3)) * MP * 8 + (size_t)rg * 8 + (col & 7)) = ov;
}

// ---------------- N-split x K-split GEMM -> bf16 partials, 32-col tiles, 256 blocks ----------------
// grid (32, 8): n0 = x*32, ksl = y; slice K = NOUTER*128.
template<int NOUTER>
__global__ __launch_bounds__(512) void k_gemm_part32(
    const u16* __restrict__ fa, const float* __restrict__ W, int wN,
    u16* __restrict__ outp)
{
  __shared__ u16 lds[2 * 32 * SW32];
  int n0 = blockIdx.x * 32;
  int ksl = blockIdx.y;
  const u16* fa_s = fa + (size_t)(ksl * NOUTER * 16) * MP * 8;
  const float* W_s = W + (size_t)(ksl * NOUTER * 128) * wN;
  f4 acc[4][2];
  #pragma unroll
  for (int i = 0; i < 4; ++i)
    #pragma unroll
    for (int j = 0; j < 2; ++j) acc[i][j] = (f4){0.f,0.f,0.f,0.f};
  gemm_core32w<NOUTER>(fa_s, W_s, n0, W_s, n0 + 16, wN, lds, acc);
  int tid = threadIdx.x, lane = tid & 63, wave = tid >> 6, l15 = lane & 15, g = lane >> 4;
  int wrow = wave * 64;
  #pragma unroll
  for (int mf = 0; mf < 4; ++mf)
    #pragma unroll
    for (int r = 0; r < 4; ++r){
      int row = wrow + mf * 16 + 4 * g + r;
      outp[((size_t)ksl * MP + row) * 1024 + n0 + l15] = f2bf(acc[mf][0][r]);
      outp[((size_t)ksl * MP + row) * 1024 + n0 + 16 + l15] = f2bf(acc[mf][1][r]);
    }
}

// ---------------- MLP up: gelu(n2@Wg) * (n2@Wu) -> fragA ----------------
__global__ __launch_bounds__(512) void k_mlpup(
    const u16* __restrict__ n2, const float* __restrict__ Wg, const float* __restrict__ Wu,
    u16* __restrict__ mlpf)
{
  __shared__ u16 lds[2 * 32 * SW32];
  int n0 = blockIdx.x * 16;
  f4 acc[4][2];
  #pragma unroll
  for (int i = 0; i < 4; ++i)
    #pragma unroll
    for (int j = 0; j < 2; ++j) acc[i][j] = (f4){0.f,0.f,0.f,0.f};
  gemm_core32w<8>(n2, Wg, n0, Wu, n0, DMLP, lds, acc);
  int tid = threadIdx.x, lane = tid & 63, wave = tid >> 6, l15 = lane & 15, g = lane >> 4;
  int wrow = wave * 64;
  #pragma unroll
  for (int mf = 0; mf < 4; ++mf)
    #pragma unroll
    for (int r = 0; r < 4; ++r){
      int row = wrow + mf * 16 + 4 * g + r;
      int col = n0 + l15;
      float gg = acc[mf][0][r], uu = acc[mf][1][r];
      float act = geluf_(gg) * uu;
      mlpf[((size_t)(col >> 3)) * MP * 8 + (size_t)row * 8 + (col & 7)] = f2bf(act);
    }
}

// ---------------- final: out = nf @ W_act_out + b (vectorized bh8 A-reads) ----------------
__global__ void k_out(const u16* __restrict__ nfr, const float* __restrict__ W,
                      const float* __restrict__ bias, float* __restrict__ out)
{
  int t = threadIdx.x;
  int row = blockIdx.x * 8 + (t >> 5);
  int c = t & 31;
  float acc = bias[c];
  for (int kc = 0; kc < 128; ++kc){
    bh8 v = *(const bh8*)(nfr + ((size_t)kc * MP + row) * 8);
    #pragma unroll
    for (int j = 0; j < 8; ++j)
      acc += bf2f((u16)v[j]) * W[(kc * 8 + j) * ADIMN + c];
  }
  out[row * ADIMN + c] = acc;
}

extern "C" void kernel_launch(void* const* d_in, const int* in_sizes, int n_in,
                              void* d_out, int out_size, void* d_ws, size_t ws_size,
                              hipStream_t stream)
{
  const float* pk  = (const float*)d_in[0];
  const float* pv  = (const float*)d_in[1];
  const int*   msk = (const int*)d_in[2];
  const float* xt  = (const float*)d_in[3];
  const float* ts  = (const float*)d_in[4];
  const float* Wq  = (const float*)d_in[5];
  const float* Wk  = (const float*)d_in[6];
  const float* Wv  = (const float*)d_in[7];
  const float* Wo  = (const float*)d_in[8];
  const float* Wg  = (const float*)d_in[9];
  const float* Wu  = (const float*)d_in[10];
  const float* Wd  = (const float*)d_in[11];
  const float* A1  = (const float*)d_in[12];
  const float* A2  = (const float*)d_in[13];
  const float* Af  = (const float*)d_in[14];
  const float* Wai = (const float*)d_in[15];
  const float* bai = (const float*)d_in[16];
  const float* Wao = (const float*)d_in[17];
  const float* bao = (const float*)d_in[18];
  const float* Wti = (const float*)d_in[19];
  const float* bti = (const float*)d_in[20];
  const float* Wto = (const float*)d_in[21];
  const float* bto = (const float*)d_in[22];

  char* w = (char*)d_ws;
  size_t off = 0;
  auto alloc = [&](size_t bytes) -> char* {
    char* p = w + off; off += (bytes + 255) & ~(size_t)255; return p;
  };
  float* temb  = (float*)alloc((size_t)BATCH * HIDN * 4);
  float* ttmp  = (float*)alloc((size_t)BATCH * HIDN * 4);
  float* cond  = (float*)alloc((size_t)BATCH * HIDN * 4);
  int*   offs  = (int*)alloc(BATCH * 4);
  float* ropec = (float*)alloc((size_t)BATCH * AHOR * 128 * 4);
  float* ropes = (float*)alloc((size_t)BATCH * AHOR * 128 * 4);
  float* ada   = (float*)alloc(ADASL * 4);
  float* adap  = (float*)alloc(8 * ADASL * 4);
  float* h     = (float*)alloc((size_t)MR * HIDN * 4);
  float* h1    = (float*)alloc((size_t)MR * HIDN * 4);
  u16*   n1    = (u16*)alloc((size_t)128 * MP * 8 * 2);
  u16*   n2    = (u16*)alloc((size_t)128 * MP * 8 * 2);
  u16*   qf    = (u16*)alloc((size_t)BATCH * 32 * MP * 8 * 2);
  u16*   kss   = (u16*)alloc((size_t)BATCH * AHOR * HD * 2);
  u16*   vss   = (u16*)alloc((size_t)BATCH * AHOR * HD * 2);
  u16*   opart = (u16*)alloc((size_t)BATCH * NSTR * MR * HD * 2);
  float* mrow  = (float*)alloc((size_t)BATCH * NSTR * MP * 4);
  float* lrow  = (float*)alloc((size_t)BATCH * NSTR * MP * 4);
  u16*   ao    = (u16*)alloc((size_t)256 * MP * 8 * 2);
  u16*   opp   = (u16*)alloc((size_t)8 * MP * 1024 * 2);
  u16*   mlpf  = (u16*)alloc((size_t)512 * MP * 8 * 2);
  u16*   mdp   = (u16*)alloc((size_t)8 * MP * 1024 * 2);
  if (off > ws_size) return;

  k_prep<<<1, 256, 0, stream>>>(msk, ts, temb, offs, ropec, ropes);
  k_tproj<<<32, 256, 0, stream>>>(temb, Wti, bti, ttmp);
  k_tproj<<<32, 256, 0, stream>>>(ttmp, Wto, bto, cond);
  k_ada_part<<<dim3(3, 37, 8), 256, 0, stream>>>(cond, A1, A2, Af, adap);
  k_ada_red<<<444, 256, 0, stream>>>(adap, ada);
  k_hin<<<MR, 256, 0, stream>>>(xt, Wai, bai, h);

  auto AP = [&](int y, int comp){ return ada + ((size_t)y * 3 + comp) * BATCH * HIDN; };

  k_resnorm<<<256, 256, 0, stream>>>(0, 0, h, nullptr, nullptr, AP(0,0), AP(0,1), nullptr, n1);

  for (int l = 0; l < NLAY; ++l){
    k_qkvrope<<<80, 512, 0, stream>>>(n1, Wq + (size_t)l * HIDN * NHEAD * HD,
                                      Wk + (size_t)l * HIDN * HD, Wv + (size_t)l * HIDN * HD,
                                      ropec, ropes, qf, kss, vss);
    k_attn<<<dim3(NSTR, BATCH, 2), 512, 0, stream>>>(qf, kss, vss, pk, pv, msk, l, opart, mrow, lrow);
    k_comb<<<dim3(100, BATCH), 256, 0, stream>>>(opart, mrow, lrow, ao);
    k_gemm_part32<2><<<dim3(32, 8), 512, 0, stream>>>(ao, Wo + (size_t)l * 2048 * 1024, 1024, opp);
    k_resnorm<<<256, 256, 0, stream>>>(1, 8, h, opp, AP(l,2), AP(NLAY+l,0), AP(NLAY+l,1), h1, n2);
    k_mlpup<<<256, 512, 0, stream>>>(n2, Wg + (size_t)l * HIDN * DMLP, Wu + (size_t)l * HIDN * DMLP, mlpf);
    k_gemm_part32<4><<<dim3(32, 8), 512, 0, stream>>>(mlpf, Wd + (size_t)l * DMLP * 1024, 1024, mdp);
    const float* nsc = (l < NLAY - 1) ? AP(l + 1, 0) : AP(36, 0);
    const float* nsh = (l < NLAY - 1) ? AP(l + 1, 1) : AP(36, 1);
    k_resnorm<<<256, 256, 0, stream>>>(2, 8, h1, mdp, AP(NLAY+l,2), nsc, nsh, h, n1);
  }
  k_out<<<50, 256, 0, stream>>>(n1, Wao, bao, (float*)d_out);
}